// Round 8
// baseline (566.656 us; speedup 1.0000x reference)
//
#include <hip/hip_runtime.h>

typedef _Float16 half8 __attribute__((ext_vector_type(8)));
typedef _Float16 half4 __attribute__((ext_vector_type(4)));
typedef _Float16 half2 __attribute__((ext_vector_type(2)));
typedef float    f32x4 __attribute__((ext_vector_type(4)));
typedef float    f32x2 __attribute__((ext_vector_type(2)));
typedef unsigned u32x2 __attribute__((ext_vector_type(2)));
typedef unsigned u32x4 __attribute__((ext_vector_type(4)));

#define TMASK ((1u << 19) - 1u)       // T = 2^19
#define HSTRIDE 136                    // fallback-kernel LDS stride
constexpr float SCALE = 65536.0f;      // activation scale: keeps f16 out of subnormal range
constexpr float INV_SCALE = 1.0f / 65536.0f;

// Dense-remap geometry, coarse levels 0..7 (s = res+2 guards x=1.0 edge).
// Brick mode: 32B bricks (xs,y,z) = entries (4xs..4xs+3) x (y,y+1) x z,
//   dword j = 2*xoff + yoff -> all 8 corners from 2x16B loads.
__device__ __constant__ unsigned SC_TAB[8]   = {18, 22, 27, 34, 42, 52, 66, 82};
__device__ __constant__ unsigned SX4_TAB[8]  = {5, 6, 7, 9, 11, 13, 17, 21};
__device__ __constant__ unsigned DOFF16_TAB[8] = {0, 1620, 4524, 9627, 20031, 39435, 74587, 148639};
#define DSLOT_TOTAL 289843u

// ---------------------------------------------------------------------------
// Merged prep + dense-brick build: one launch. Blocks [0,8192): fine
// fp32->f16 convert; [8192,8222): weights/biases; [8222,...): dense bricks.
// ---------------------------------------------------------------------------
__global__ void prep_dense_kernel(const float* __restrict__ W0, const float* __restrict__ W1,
                                  const float* __restrict__ W2, const float* __restrict__ W3,
                                  const float* __restrict__ Wm,
                                  const float* __restrict__ b0, const float* __restrict__ b1,
                                  const float* __restrict__ b2, const float* __restrict__ b3,
                                  const float* __restrict__ bm,
                                  _Float16* __restrict__ wsW, float* __restrict__ wsB,
                                  const float* __restrict__ tables, _Float16* __restrict__ tabF,
                                  unsigned* __restrict__ dense)
{
    const int bid = (int)blockIdx.x;
    if (bid < 8192) {
        size_t i = (size_t)bid * 256 + threadIdx.x;
        f32x4 v = ((const f32x4*)(tables + (size_t)8 * 524288 * 2))[i];
        half4 o;
        o[0] = (_Float16)(v.x * SCALE);
        o[1] = (_Float16)(v.y * SCALE);
        o[2] = (_Float16)(v.z * SCALE);
        o[3] = (_Float16)(v.w * SCALE);
        ((half4*)tabF)[i] = o;
        return;
    }
    if (bid < 8222) {
        int gid = (bid - 8192) * 256 + threadIdx.x;
        if (gid < 6912) {                       // 108 tiles * 64 lanes
            int tile = gid >> 6, lane = gid & 63;
            const float* W; int K, N, toff;
            if (tile < 8)        { W = W0; K = 32;  N = 128; toff = 0;   }
            else if (tile < 40)  { W = W1; K = 128; N = 128; toff = 8;   }
            else if (tile < 72)  { W = W2; K = 128; N = 128; toff = 40;  }
            else if (tile < 104) { W = W3; K = 128; N = 128; toff = 72;  }
            else                 { W = Wm; K = 128; N = 4;   toff = 104; }
            int tt = tile - toff;
            int KT = K >> 5;
            int nt = tt / KT, kt = tt - nt * KT;
            int n = nt * 16 + (lane & 15);
            int kbase = kt * 32 + (lane >> 4) * 8;
            half8 v;
            #pragma unroll
            for (int j = 0; j < 8; j++) {
                int k = kbase + j;
                float w = (n < N) ? W[k * N + n] : 0.0f;
                v[j] = (_Float16)w;
            }
            *(half8*)(wsW + (size_t)gid * 8) = v;
        } else if (gid < 6912 + 528) {
            int i = gid - 6912;
            float v;
            if (i < 512) {
                int layer = i >> 7, n = i & 127;
                const float* b = (layer == 0) ? b0 : (layer == 1) ? b1 : (layer == 2) ? b2 : b3;
                v = b[n] * SCALE;
            } else {
                int n = i - 512;
                v = (n < 4) ? bm[n] * SCALE : 0.0f;
            }
            wsB[i] = v;
        }
        return;
    }
    // dense brick build
    unsigned e = (unsigned)(bid - 8222) * 256 + threadIdx.x;
    if (e >= DSLOT_TOTAL * 8u) return;
    unsigned brick = e >> 3, j = e & 7u;
    int l = 0;
    #pragma unroll
    for (int i = 1; i < 8; i++) l += (brick >= DOFF16_TAB[i]) ? 1 : 0;
    unsigned local = brick - DOFF16_TAB[l];
    unsigned s = SC_TAB[l], sx4 = SX4_TAB[l];
    unsigned plane = sx4 * s;
    unsigned z = local / plane;
    unsigned rem = local - z * plane;
    unsigned yb = rem / sx4;
    unsigned xs = rem - yb * sx4;
    unsigned x = xs * 4u + (j >> 1);
    unsigned y = yb + (j & 1u);
    unsigned h = (x ^ (y * 2654435761u) ^ (z * 805459861u)) & TMASK;
    const float* src = tables + ((size_t)l * 524288u + h) * 2;
    half2 o; o[0] = (_Float16)(src[0] * SCALE); o[1] = (_Float16)(src[1] * SCALE);
    union { half2 h2; unsigned u; } cv; cv.h2 = o;
    dense[e] = cv.u;
}

// ---------------------------------------------------------------------------
// Legacy prep (weights-only path for fallback tier).
// ---------------------------------------------------------------------------
__global__ void prep_kernel(const float* __restrict__ W0, const float* __restrict__ W1,
                            const float* __restrict__ W2, const float* __restrict__ W3,
                            const float* __restrict__ Wm,
                            const float* __restrict__ b0, const float* __restrict__ b1,
                            const float* __restrict__ b2, const float* __restrict__ b3,
                            const float* __restrict__ bm,
                            _Float16* __restrict__ wsW, float* __restrict__ wsB,
                            const float* __restrict__ tabSrc, _Float16* __restrict__ tabF,
                            int tabBlocks)
{
    if ((int)blockIdx.x < tabBlocks) {
        size_t i = (size_t)blockIdx.x * 256 + threadIdx.x;
        f32x4 v = ((const f32x4*)tabSrc)[i];
        half4 o;
        o[0] = (_Float16)(v.x * SCALE);
        o[1] = (_Float16)(v.y * SCALE);
        o[2] = (_Float16)(v.z * SCALE);
        o[3] = (_Float16)(v.w * SCALE);
        ((half4*)tabF)[i] = o;
        return;
    }
    int gid = ((int)blockIdx.x - tabBlocks) * 256 + threadIdx.x;
    if (gid < 6912) {
        int tile = gid >> 6, lane = gid & 63;
        const float* W; int K, N, toff;
        if (tile < 8)        { W = W0; K = 32;  N = 128; toff = 0;   }
        else if (tile < 40)  { W = W1; K = 128; N = 128; toff = 8;   }
        else if (tile < 72)  { W = W2; K = 128; N = 128; toff = 40;  }
        else if (tile < 104) { W = W3; K = 128; N = 128; toff = 72;  }
        else                 { W = Wm; K = 128; N = 4;   toff = 104; }
        int tt = tile - toff;
        int KT = K >> 5;
        int nt = tt / KT, kt = tt - nt * KT;
        int n = nt * 16 + (lane & 15);
        int kbase = kt * 32 + (lane >> 4) * 8;
        half8 v;
        #pragma unroll
        for (int j = 0; j < 8; j++) {
            int k = kbase + j;
            float w = (n < N) ? W[k * N + n] : 0.0f;
            v[j] = (_Float16)w;
        }
        *(half8*)(wsW + (size_t)gid * 8) = v;
    } else if (gid < 6912 + 528) {
        int i = gid - 6912;
        float v;
        if (i < 512) {
            int layer = i >> 7, n = i & 127;
            const float* b = (layer == 0) ? b0 : (layer == 1) ? b1 : (layer == 2) ? b2 : b3;
            v = b[n] * SCALE;
        } else {
            int n = i - 512;
            v = (n < 4) ? bm[n] * SCALE : 0.0f;
        }
        wsB[i] = v;
    }
}

// ---------------------------------------------------------------------------
// Encode (brick) — unchanged from R7: at structural floor per line model.
// ---------------------------------------------------------------------------
struct PtStateB {
    unsigned fI0[4];
    unsigned xm1, fSel;         // fSel: s0[g] in bits 2g..2g+1, m in 8..9, carry in 10
    unsigned cOff0, cOff1;      // dword offsets of coarse 16B groups (z0, z1)
    float fF[3], fC[3];
};
struct PtLoadsB {
    u32x4 fB[4]; u32x4 cZ[2]; unsigned fX[4];
};

__global__ __launch_bounds__(256) void encode_brick(
    const float* __restrict__ pos, const float* __restrict__ bmn, const float* __restrict__ bmx,
    const _Float16* __restrict__ tabFine, const unsigned* __restrict__ dense,
    _Float16* __restrict__ feat, int npts)
{
    const int lvl0 = (int)(blockIdx.x & 7);
    const int t = (int)threadIdx.x;
    const long pb = (long)(blockIdx.x >> 3) * 2048 + t;   // points pb + k*256, k=0..7
    const float bx = bmn[0], by = bmn[1], bz = bmn[2];
    const float dxr = bmx[0] - bx, dyr = bmx[1] - by, dzr = bmx[2] - bz;
    constexpr float RESL[16] = {16.f, 20.f, 25.f, 32.f, 40.f, 50.f, 64.f, 80.f,
                                101.f, 128.f, 161.f, 203.f, 256.f, 322.f, 406.f, 512.f};
    const int l1 = lvl0 + 8;
    const _Float16* tblB = tabFine + ((size_t)lvl0 << 20);
    const float resF = RESL[l1], resC = RESL[lvl0];
    const unsigned sx4 = SX4_TAB[lvl0];
    const unsigned plane8 = sx4 * SC_TAB[lvl0] * 8u;      // dwords per z-plane of bricks
    const unsigned* dlvl = dense + (size_t)DOFF16_TAB[lvl0] * 8u;

    auto computePt = [&](long p, PtStateB& S) {
        const float nx = (pos[p * 3 + 0] - bx) / dxr;
        const float ny = (pos[p * 3 + 1] - by) / dyr;
        const float nz = (pos[p * 3 + 2] - bz) / dzr;
        {   // fine (hashed, 16B-block trick)
            float xs = nx * resF, ys = ny * resF, zs = nz * resF;
            float fx = floorf(xs), fy = floorf(ys), fz = floorf(zs);
            unsigned xi = (unsigned)fx, yi = (unsigned)fy, zi = (unsigned)fz;
            S.fF[0] = xs - fx; S.fF[1] = ys - fy; S.fF[2] = zs - fz;
            unsigned hy0 = yi * 2654435761u, hy1 = (yi + 1u) * 2654435761u;
            unsigned hz0 = zi * 805459861u,  hz1 = (zi + 1u) * 805459861u;
            unsigned hyz[4] = {hy0 ^ hz0, hy1 ^ hz0, hy0 ^ hz1, hy1 ^ hz1};
            unsigned xm1 = xi ^ (xi + 1u);
            unsigned sel = 0;
            #pragma unroll
            for (int g = 0; g < 4; g++) {
                unsigned i0 = (xi ^ hyz[g]) & TMASK;
                S.fI0[g] = i0;
                sel |= (i0 & 3u) << (2 * g);
            }
            sel |= (xm1 & 3u) << 8;
            if ((xi & 3u) == 3u) sel |= 1024u;
            S.fSel = sel;
            S.xm1 = xm1;
        }
        {   // coarse (y-dup bricks)
            float xs = nx * resC, ys = ny * resC, zs = nz * resC;
            float fx = floorf(xs), fy = floorf(ys), fz = floorf(zs);
            unsigned xi = (unsigned)fx, yi = (unsigned)fy, zi = (unsigned)fz;
            S.fC[0] = xs - fx; S.fC[1] = ys - fy; S.fC[2] = zs - fz;
            unsigned o0 = ((xi >> 2) + sx4 * yi) * 8u + plane8 * zi + (xi & 3u) * 2u;
            S.cOff0 = o0;
            S.cOff1 = o0 + plane8;
        }
    };

    auto issuePt = [&](const PtStateB& S, PtLoadsB& L) {
        #pragma unroll
        for (int g = 0; g < 4; g++)
            L.fB[g] = *(const u32x4*)(tblB + (size_t)(S.fI0[g] >> 2) * 8);
        __builtin_memcpy(&L.cZ[0], dlvl + S.cOff0, 16);
        __builtin_memcpy(&L.cZ[1], dlvl + S.cOff1, 16);
        if (S.fSel & 1024u) {
            #pragma unroll
            for (int g = 0; g < 4; g++)
                L.fX[g] = *(const unsigned*)(tblB + (size_t)((S.fI0[g] ^ S.xm1) & TMASK) * 2);
        }
    };

    auto consumePt = [&](const PtStateB& S, const PtLoadsB& L, long p) {
        {   // fine
            float tx = S.fF[0], ty = S.fF[1], tz = S.fF[2];
            float wyz[4] = {(1.0f - ty) * (1.0f - tz), ty * (1.0f - tz),
                            (1.0f - ty) * tz,          ty * tz};
            unsigned selw = S.fSel;
            unsigned m = (selw >> 8) & 3u;
            bool carry = (selw & 1024u) != 0u;
            float b0 = 0.0f, b1 = 0.0f;
            #pragma unroll
            for (int g = 0; g < 4; g++) {
                u32x4 v = L.fB[g];
                unsigned s0 = (selw >> (2 * g)) & 3u;
                unsigned s1 = s0 ^ m;
                unsigned a0_ = (s0 & 2u) ? v[2] : v[0];
                unsigned b0_ = (s0 & 2u) ? v[3] : v[1];
                unsigned e0  = (s0 & 1u) ? b0_ : a0_;
                unsigned a1_ = (s1 & 2u) ? v[2] : v[0];
                unsigned b1_ = (s1 & 2u) ? v[3] : v[1];
                unsigned e1s = (s1 & 1u) ? b1_ : a1_;
                unsigned e1  = carry ? L.fX[g] : e1s;
                union { unsigned u; half2 h; } u0, u1;
                u0.u = e0; u1.u = e1;
                float w0 = wyz[g] * (1.0f - tx), w1 = wyz[g] * tx;
                b0 += w0 * (float)u0.h[0] + w1 * (float)u1.h[0];
                b1 += w0 * (float)u0.h[1] + w1 * (float)u1.h[1];
            }
            half2 ov2; ov2[0] = (_Float16)b0; ov2[1] = (_Float16)b1;
            union { half2 h; unsigned u; } cv; cv.h = ov2;
            __builtin_nontemporal_store(cv.u, (unsigned*)(feat + ((size_t)l1 * npts + p) * 2));
        }
        {   // coarse: corner g=(ybit, zbit); u0 = cZ[z][ybit], u1 = cZ[z][2+ybit]
            float tx = S.fC[0], ty = S.fC[1], tz = S.fC[2];
            float wyz[4] = {(1.0f - ty) * (1.0f - tz), ty * (1.0f - tz),
                            (1.0f - ty) * tz,          ty * tz};
            float a0 = 0.0f, a1 = 0.0f;
            #pragma unroll
            for (int g = 0; g < 4; g++) {
                union { unsigned u; half2 h; } u0, u1;
                u0.u = L.cZ[g >> 1][g & 1];
                u1.u = L.cZ[g >> 1][2 + (g & 1)];
                float w0 = wyz[g] * (1.0f - tx), w1 = wyz[g] * tx;
                a0 += w0 * (float)u0.h[0] + w1 * (float)u1.h[0];
                a1 += w0 * (float)u0.h[1] + w1 * (float)u1.h[1];
            }
            half2 ov2; ov2[0] = (_Float16)a0; ov2[1] = (_Float16)a1;
            union { half2 h; unsigned u; } cv; cv.h = ov2;
            __builtin_nontemporal_store(cv.u, (unsigned*)(feat + ((size_t)lvl0 * npts + p) * 2));
        }
    };

    // ---- software pipeline: window = 2 points (1 consuming + 1 in flight) ----
    PtStateB sA, sB; PtLoadsB lA, lB;
    computePt(pb + 0 * 256, sA); issuePt(sA, lA);
    computePt(pb + 1 * 256, sB); issuePt(sB, lB);
    #pragma unroll
    for (int k = 0; k < 6; k++) {
        if ((k & 1) == 0) {
            consumePt(sA, lA, pb + (long)k * 256);
            computePt(pb + (long)(k + 2) * 256, sA); issuePt(sA, lA);
        } else {
            consumePt(sB, lB, pb + (long)k * 256);
            computePt(pb + (long)(k + 2) * 256, sB); issuePt(sB, lB);
        }
    }
    consumePt(sA, lA, pb + 6 * 256);
    consumePt(sB, lB, pb + 7 * 256);
}

// ---------------------------------------------------------------------------
// MLP kernel R16: LDS weight staging. Theory: mlp was bound by the same
// L2-line-service rate as encode — per-wave weight re-reads were 108 KB x
// 16384 waves = 1.77 GB = 27.6M lines (~150us at the measured 184 G lines/s).
// Fix: stage each layer's tiles into a 32 KB LDS buffer once per BLOCK
// (x4 wave reuse -> 6.9M lines), prefetching the next layer into registers
// DURING the current layer's MFMA so global latency hides under compute.
// Single wbuf, two barriers/layer (read-done, staged). LDS 69.6+32 = 102 KB
// -> 1 block/CU (4 waves) — acceptable: this regime pays for line count,
// not concurrency (R2/R4/R5/R6 evidence).
// ---------------------------------------------------------------------------
#define ELANE 68   // dwords per lane: 64 payload + 4 pad; 272B (16B-aligned)

template<int KT>
__device__ __forceinline__ void layer_fwd4(half8 b[4][4], const half8* wl,
                                           const float* __restrict__ wsB, int li,
                                           unsigned* __restrict__ eb, int lane, int quad,
                                           unsigned srcA, unsigned srcB, int mtbase)
{
    unsigned* wptr = eb + lane * ELANE;
    #pragma unroll
    for (int mt = 0; mt < 8; mt++) {
        f32x4 bias = *(const f32x4*)&wsB[li * 128 + mt * 16 + quad * 4];
        half8 w[KT];
        #pragma unroll
        for (int kt = 0; kt < KT; kt++)
            w[kt] = wl[(mt * KT + kt) * 64 + lane];
        f32x4 acc[4] = {bias, bias, bias, bias};
        #pragma unroll
        for (int nt = 0; nt < 4; nt++)
            #pragma unroll
            for (int kt = 0; kt < KT; kt++)
                acc[nt] = __builtin_amdgcn_mfma_f32_16x16x32_f16(w[kt], b[nt][kt], acc[nt], 0, 0, 0);
        #pragma unroll
        for (int np = 0; np < 2; np++) {
            union { _Float16 h[8]; u32x4 v; } pk;
            #pragma unroll
            for (int r = 0; r < 4; r++) {
                pk.h[r]     = (_Float16)fmaxf(acc[2 * np][r],     0.0f);
                pk.h[4 + r] = (_Float16)fmaxf(acc[2 * np + 1][r], 0.0f);
            }
            *(u32x4*)(wptr + mt * 8 + np * 4) = pk.v;
        }
    }
    #pragma unroll
    for (int ktp = 0; ktp < 4; ktp++) {
        int mt = 2 * ktp + mtbase;
        u32x4 rA0 = *(const u32x4*)(eb + srcA * ELANE + mt * 8);
        u32x4 rA1 = *(const u32x4*)(eb + srcA * ELANE + mt * 8 + 4);
        u32x4 rB0 = *(const u32x4*)(eb + srcB * ELANE + mt * 8);
        u32x4 rB1 = *(const u32x4*)(eb + srcB * ELANE + mt * 8 + 4);
        union { u32x4 v; half8 h; } c0, c1, c2, c3;
        c0.v = (u32x4){rA0[0], rA0[1], rB0[0], rB0[1]};
        c1.v = (u32x4){rA0[2], rA0[3], rB0[2], rB0[3]};
        c2.v = (u32x4){rA1[0], rA1[1], rB1[0], rB1[1]};
        c3.v = (u32x4){rA1[2], rA1[3], rB1[2], rB1[3]};
        b[0][ktp] = c0.h;
        b[1][ktp] = c1.h;
        b[2][ktp] = c2.h;
        b[3][ktp] = c3.h;
    }
}

__global__ __launch_bounds__(256) void mlp_kernel(
    const unsigned* __restrict__ feat32, const half8* __restrict__ wf,
    const float* __restrict__ wsB, float* __restrict__ out, int npts)
{
    __shared__ __align__(16) unsigned ebuf[4 * 64 * ELANE];
    __shared__ __align__(16) _Float16 wbuf_raw[2048 * 8];   // 32 KB: one layer (<=32 tiles)
    half8* wbuf = (half8*)wbuf_raw;
    const int t = threadIdx.x;
    const int lane = t & 63, wv = t >> 6;
    const int col = lane & 15, quad = lane >> 4;
    const long base = (long)blockIdx.x * 256 + wv * 64;
    unsigned* eb = ebuf + wv * (64 * ELANE);
    const int q1 = 2 * (quad & 1);
    const unsigned srcA = (unsigned)(col + 16 * q1);
    const unsigned srcB = (unsigned)(col + 16 * (q1 + 1));
    const int mtbase = quad >> 1;

    // stage layer 0 (8 tiles = 512 half8, 2 per thread)
    {
        half8 s0 = wf[t];
        half8 s1 = wf[256 + t];
        wbuf[t] = s0;
        wbuf[256 + t] = s1;
    }

    half8 b[4][4];
    #pragma unroll
    for (int nt = 0; nt < 4; nt++) {
        const long pt = base + nt * 16 + col;
        union { unsigned u4[4]; half8 v; } cv;
        #pragma unroll
        for (int jj = 0; jj < 4; jj++)
            cv.u4[jj] = feat32[(size_t)(quad * 4 + jj) * npts + pt];
        b[nt][0] = cv.v;
    }
    __syncthreads();

    half8 stg[8];

    // layer 0 (32->128), prefetch layer 1 (tiles 8..39 -> h8 512..2559)
    #pragma unroll
    for (int i = 0; i < 8; i++) stg[i] = wf[512 + i * 256 + t];
    layer_fwd4<1>(b, wbuf, wsB, 0, eb, lane, quad, srcA, srcB, mtbase);
    __syncthreads();
    #pragma unroll
    for (int i = 0; i < 8; i++) wbuf[i * 256 + t] = stg[i];
    __syncthreads();

    // layer 1 (128->128), prefetch layer 2 (tiles 40..71 -> h8 2560..4607)
    #pragma unroll
    for (int i = 0; i < 8; i++) stg[i] = wf[2560 + i * 256 + t];
    layer_fwd4<4>(b, wbuf, wsB, 1, eb, lane, quad, srcA, srcB, mtbase);
    __syncthreads();
    #pragma unroll
    for (int i = 0; i < 8; i++) wbuf[i * 256 + t] = stg[i];
    __syncthreads();

    // layer 2, prefetch layer 3 (tiles 72..103 -> h8 4608..6655)
    #pragma unroll
    for (int i = 0; i < 8; i++) stg[i] = wf[4608 + i * 256 + t];
    layer_fwd4<4>(b, wbuf, wsB, 2, eb, lane, quad, srcA, srcB, mtbase);
    __syncthreads();
    #pragma unroll
    for (int i = 0; i < 8; i++) wbuf[i * 256 + t] = stg[i];
    __syncthreads();

    // layer 3, prefetch out layer (tiles 104..107 -> h8 6656..6911, 1/thread)
    half8 so = wf[6656 + t];
    layer_fwd4<4>(b, wbuf, wsB, 3, eb, lane, quad, srcA, srcB, mtbase);
    __syncthreads();
    wbuf[t] = so;
    __syncthreads();

    // out layer (128->4) from LDS
    f32x4 biaso = *(const f32x4*)&wsB[512 + quad * 4];
    f32x4 acco[4] = {biaso, biaso, biaso, biaso};
    #pragma unroll
    for (int kt = 0; kt < 4; kt++) {
        half8 w = wbuf[kt * 64 + lane];
        #pragma unroll
        for (int nt = 0; nt < 4; nt++)
            acco[nt] = __builtin_amdgcn_mfma_f32_16x16x32_f16(w, b[nt][kt], acco[nt], 0, 0, 0);
    }
    if (quad == 0) {
        #pragma unroll
        for (int nt = 0; nt < 4; nt++) {
            f32x4 v;
            #pragma unroll
            for (int r = 0; r < 4; r++) v[r] = acco[nt][r] * INV_SCALE;
            *(f32x4*)(out + (base + nt * 16 + col) * 4) = v;
        }
    }
}

// ---------------------------------------------------------------------------
// Fallback path (ws too small): R1-style fused kernel, unchanged.
// ---------------------------------------------------------------------------
template<int KT, int TOFF, bool RELU>
__device__ __forceinline__ void mlp_layer(_Float16* h, const half8* __restrict__ wf,
                                          const float* __restrict__ wsB, int layerIdx,
                                          int m0, int lane)
{
    const int col = lane & 15, quad = lane >> 4;
    const int sw = (col & 3) << 3;
    half8 a[2][KT];
    #pragma unroll
    for (int mt = 0; mt < 2; mt++)
        #pragma unroll
        for (int kt = 0; kt < KT; kt++)
            a[mt][kt] = *(const half8*)&h[(m0 + mt * 16 + col) * HSTRIDE + ((kt * 32 + quad * 8) ^ sw)];
    f32x4 acc[2][8];
    #pragma unroll
    for (int nt = 0; nt < 8; nt++) {
        float bv = wsB[layerIdx * 128 + nt * 16 + col];
        acc[0][nt] = (f32x4){bv, bv, bv, bv};
        acc[1][nt] = (f32x4){bv, bv, bv, bv};
    }
    #pragma unroll
    for (int nt = 0; nt < 8; nt++) {
        half8 b[KT];
        #pragma unroll
        for (int kt = 0; kt < KT; kt++)
            b[kt] = wf[(size_t)(TOFF + nt * KT + kt) * 64 + lane];
        #pragma unroll
        for (int mt = 0; mt < 2; mt++)
            #pragma unroll
            for (int kt = 0; kt < KT; kt++)
                acc[mt][nt] = __builtin_amdgcn_mfma_f32_16x16x32_f16(a[mt][kt], b[kt], acc[mt][nt], 0, 0, 0);
    }
    #pragma unroll
    for (int mt = 0; mt < 2; mt++)
        #pragma unroll
        for (int nt = 0; nt < 8; nt++) {
            f32x4 v = acc[mt][nt];
            #pragma unroll
            for (int r = 0; r < 4; r++) {
                float x = v[r];
                if (RELU) x = fmaxf(x, 0.0f);
                h[(m0 + mt * 16 + quad * 4 + r) * HSTRIDE + ((nt * 16 + col) ^ (r << 3))] = (_Float16)x;
            }
        }
}

__global__ __launch_bounds__(256, 2) void fused_kernel(
    const float* __restrict__ pos, const float* __restrict__ bmn, const float* __restrict__ bmx,
    const float* __restrict__ tables, const half8* __restrict__ wf, const float* __restrict__ wsB,
    float* __restrict__ out)
{
    __shared__ _Float16 hbuf[128 * HSTRIDE];
    __shared__ float outstage[512];
    const int t = threadIdx.x;
    const long base = (long)blockIdx.x * 128;
    {
        const int p = t >> 1, hh = t & 1;
        const long gp = base + p;
        const float b0x = bmn[0], b0y = bmn[1], b0z = bmn[2];
        const float nx = (pos[gp * 3 + 0] - b0x) / (bmx[0] - b0x);
        const float ny = (pos[gp * 3 + 1] - b0y) / (bmx[1] - b0y);
        const float nz = (pos[gp * 3 + 2] - b0z) / (bmx[2] - b0z);
        constexpr float RLO[8] = {16.f, 20.f, 25.f, 32.f, 40.f, 50.f, 64.f, 80.f};
        constexpr float RHI[8] = {101.f, 128.f, 161.f, 203.f, 256.f, 322.f, 406.f, 512.f};
        half8 fa, fb;
        #pragma unroll
        for (int li = 0; li < 8; li++) {
            const float res = hh ? RHI[li] : RLO[li];
            const float* tbl = tables + ((size_t)(hh * 8 + li) << 20);
            float xs = nx * res, ys = ny * res, zs = nz * res;
            float fx = floorf(xs), fy = floorf(ys), fz = floorf(zs);
            unsigned xi = (unsigned)fx, yi = (unsigned)fy, zi = (unsigned)fz;
            float tx = xs - fx, ty = ys - fy, tz = zs - fz;
            unsigned hx[2] = {xi, xi + 1u};
            unsigned hy[2] = {yi * 2654435761u, (yi + 1u) * 2654435761u};
            unsigned hz[2] = {zi * 805459861u, (zi + 1u) * 805459861u};
            float wx[2] = {1.0f - tx, tx}, wy[2] = {1.0f - ty, ty}, wz[2] = {1.0f - tz, tz};
            float a0 = 0.0f, a1 = 0.0f;
            #pragma unroll
            for (int c = 0; c < 8; c++) {
                unsigned hsh = hx[c & 1] ^ hy[(c >> 1) & 1] ^ hz[c >> 2];
                unsigned idx = hsh & TMASK;
                f32x2 f = *(const f32x2*)(tbl + (size_t)idx * 2);
                float w = wx[c & 1] * wy[(c >> 1) & 1] * wz[c >> 2];
                a0 += w * f.x;
                a1 += w * f.y;
            }
            if (li < 4) { fa[2 * li]       = (_Float16)(a0 * SCALE); fa[2 * li + 1]       = (_Float16)(a1 * SCALE); }
            else        { fb[2 * (li - 4)] = (_Float16)(a0 * SCALE); fb[2 * (li - 4) + 1] = (_Float16)(a1 * SCALE); }
        }
        const int sw = (p & 3) << 3;
        *(half8*)&hbuf[p * HSTRIDE + ((hh * 16) ^ sw)]       = fa;
        *(half8*)&hbuf[p * HSTRIDE + (((hh * 16) + 8) ^ sw)] = fb;
    }
    __syncthreads();
    {
        const int lane = t & 63;
        const int m0 = (t >> 6) * 32;
        mlp_layer<1, 0,   true>(hbuf, wf, wsB, 0, m0, lane);
        mlp_layer<4, 8,   true>(hbuf, wf, wsB, 1, m0, lane);
        mlp_layer<4, 40,  true>(hbuf, wf, wsB, 2, m0, lane);
        mlp_layer<4, 72,  true>(hbuf, wf, wsB, 3, m0, lane);
        const int col = lane & 15, quad = lane >> 4;
        const int sw = (col & 3) << 3;
        half8 a[2][4];
        #pragma unroll
        for (int mt = 0; mt < 2; mt++)
            #pragma unroll
            for (int kt = 0; kt < 4; kt++)
                a[mt][kt] = *(const half8*)&hbuf[(m0 + mt * 16 + col) * HSTRIDE + ((kt * 32 + quad * 8) ^ sw)];
        float bv = wsB[512 + col];
        f32x4 acc[2] = {(f32x4){bv, bv, bv, bv}, (f32x4){bv, bv, bv, bv}};
        #pragma unroll
        for (int kt = 0; kt < 4; kt++) {
            half8 bfr = wf[(size_t)(104 + kt) * 64 + lane];
            #pragma unroll
            for (int mt = 0; mt < 2; mt++)
                acc[mt] = __builtin_amdgcn_mfma_f32_16x16x32_f16(a[mt][kt], bfr, acc[mt], 0, 0, 0);
        }
        if (col < 4) {
            #pragma unroll
            for (int mt = 0; mt < 2; mt++)
                #pragma unroll
                for (int r = 0; r < 4; r++)
                    outstage[(m0 + mt * 16 + quad * 4 + r) * 4 + col] = acc[mt][r] * INV_SCALE;
        }
    }
    __syncthreads();
    if (t < 128) {
        f32x4 v = ((const f32x4*)outstage)[t];
        *(f32x4*)(out + (base + t) * 4) = v;
    }
}

extern "C" void kernel_launch(void* const* d_in, const int* in_sizes, int n_in,
                              void* d_out, int out_size, void* d_ws, size_t ws_size,
                              hipStream_t stream) {
    const float* pos    = (const float*)d_in[0];
    const float* bmn    = (const float*)d_in[1];
    const float* bmx    = (const float*)d_in[2];
    const float* tables = (const float*)d_in[3];
    const float* W0 = (const float*)d_in[4];
    const float* b0 = (const float*)d_in[5];
    const float* W1 = (const float*)d_in[6];
    const float* b1 = (const float*)d_in[7];
    const float* W2 = (const float*)d_in[8];
    const float* b2 = (const float*)d_in[9];
    const float* W3 = (const float*)d_in[10];
    const float* b3 = (const float*)d_in[11];
    const float* Wm = (const float*)d_in[12];
    const float* bm = (const float*)d_in[13];

    const int N = in_sizes[0] / 3;
    const size_t featBytes    = (size_t)N * 16 * 4;             // [16][N] f16x2
    const size_t tabFineBytes = (size_t)8 * 524288 * 2 * 2;     // 16 MB f16, levels 8-15
    const size_t denseBytesB  = ((size_t)DSLOT_TOTAL * 32 + 255) & ~(size_t)255;  // ~9.3 MB bricks
    const size_t needB = featBytes + tabFineBytes + denseBytesB + 110592 + 2112;

    if (ws_size >= needB && (N % 2048) == 0) {
        _Float16* feat  = (_Float16*)d_ws;
        _Float16* tabF  = (_Float16*)((char*)d_ws + featBytes);
        unsigned* dense = (unsigned*)((char*)d_ws + featBytes + tabFineBytes);
        _Float16* wsW   = (_Float16*)((char*)d_ws + featBytes + tabFineBytes + denseBytesB);
        float*    wsB   = (float*)((char*)d_ws + featBytes + tabFineBytes + denseBytesB + 110592);
        prep_dense_kernel<<<8192 + 30 + (DSLOT_TOTAL * 8 + 255) / 256, 256, 0, stream>>>(
            W0, W1, W2, W3, Wm, b0, b1, b2, b3, bm, wsW, wsB, tables, tabF, dense);
        encode_brick<<<(N / 2048) * 8, 256, 0, stream>>>(pos, bmn, bmx, tabF,
                                                         dense, feat, N);
        mlp_kernel<<<N / 256, 256, 0, stream>>>((const unsigned*)feat, (const half8*)wsW,
                                                wsB, (float*)d_out, N);
    } else {
        _Float16* wsW = (_Float16*)d_ws;
        float*    wsB = (float*)((char*)d_ws + 110592);
        prep_kernel<<<30, 256, 0, stream>>>(W0, W1, W2, W3, Wm, b0, b1, b2, b3, bm,
                                            wsW, wsB, tables, (_Float16*)nullptr, 0);
        fused_kernel<<<N / 128, 256, 0, stream>>>(pos, bmn, bmx, tables,
                                                  (const half8*)wsW, wsB, (float*)d_out);
    }
}

// Round 11
// 507.172 us; speedup vs baseline: 1.1173x; 1.1173x over previous
//
#include <hip/hip_runtime.h>

typedef _Float16 half8 __attribute__((ext_vector_type(8)));
typedef _Float16 half4 __attribute__((ext_vector_type(4)));
typedef _Float16 half2 __attribute__((ext_vector_type(2)));
typedef float    f32x4 __attribute__((ext_vector_type(4)));
typedef float    f32x2 __attribute__((ext_vector_type(2)));
typedef unsigned u32x2 __attribute__((ext_vector_type(2)));
typedef unsigned u32x4 __attribute__((ext_vector_type(4)));

#define TMASK ((1u << 19) - 1u)       // T = 2^19
#define HSTRIDE 136                    // fallback-kernel LDS stride
constexpr float SCALE = 65536.0f;      // activation scale: keeps f16 out of subnormal range
constexpr float INV_SCALE = 1.0f / 65536.0f;

// Dense-remap geometry, coarse levels 0..7 (s = res+2 guards x=1.0 edge).
// Brick mode: 32B bricks (xs,y,z) = entries (4xs..4xs+3) x (y,y+1) x z,
//   dword j = 2*xoff + yoff -> all 8 corners from 2x16B loads.
__device__ __constant__ unsigned SC_TAB[8]   = {18, 22, 27, 34, 42, 52, 66, 82};
__device__ __constant__ unsigned SX4_TAB[8]  = {5, 6, 7, 9, 11, 13, 17, 21};
__device__ __constant__ unsigned DOFF16_TAB[8] = {0, 1620, 4524, 9627, 20031, 39435, 74587, 148639};
#define DSLOT_TOTAL 289843u

// ---------------------------------------------------------------------------
// Merged prep + dense-brick build: one launch. Blocks [0,8192): fine
// fp32->f16 convert; [8192,8222): weights/biases; [8222,...): dense bricks.
// ---------------------------------------------------------------------------
__global__ void prep_dense_kernel(const float* __restrict__ W0, const float* __restrict__ W1,
                                  const float* __restrict__ W2, const float* __restrict__ W3,
                                  const float* __restrict__ Wm,
                                  const float* __restrict__ b0, const float* __restrict__ b1,
                                  const float* __restrict__ b2, const float* __restrict__ b3,
                                  const float* __restrict__ bm,
                                  _Float16* __restrict__ wsW, float* __restrict__ wsB,
                                  const float* __restrict__ tables, _Float16* __restrict__ tabF,
                                  unsigned* __restrict__ dense)
{
    const int bid = (int)blockIdx.x;
    if (bid < 8192) {
        size_t i = (size_t)bid * 256 + threadIdx.x;
        f32x4 v = ((const f32x4*)(tables + (size_t)8 * 524288 * 2))[i];
        half4 o;
        o[0] = (_Float16)(v.x * SCALE);
        o[1] = (_Float16)(v.y * SCALE);
        o[2] = (_Float16)(v.z * SCALE);
        o[3] = (_Float16)(v.w * SCALE);
        ((half4*)tabF)[i] = o;
        return;
    }
    if (bid < 8222) {
        int gid = (bid - 8192) * 256 + threadIdx.x;
        if (gid < 6912) {                       // 108 tiles * 64 lanes
            int tile = gid >> 6, lane = gid & 63;
            const float* W; int K, N, toff;
            if (tile < 8)        { W = W0; K = 32;  N = 128; toff = 0;   }
            else if (tile < 40)  { W = W1; K = 128; N = 128; toff = 8;   }
            else if (tile < 72)  { W = W2; K = 128; N = 128; toff = 40;  }
            else if (tile < 104) { W = W3; K = 128; N = 128; toff = 72;  }
            else                 { W = Wm; K = 128; N = 4;   toff = 104; }
            int tt = tile - toff;
            int KT = K >> 5;
            int nt = tt / KT, kt = tt - nt * KT;
            int n = nt * 16 + (lane & 15);
            int kbase = kt * 32 + (lane >> 4) * 8;
            half8 v;
            #pragma unroll
            for (int j = 0; j < 8; j++) {
                int k = kbase + j;
                float w = (n < N) ? W[k * N + n] : 0.0f;
                v[j] = (_Float16)w;
            }
            *(half8*)(wsW + (size_t)gid * 8) = v;
        } else if (gid < 6912 + 528) {
            int i = gid - 6912;
            float v;
            if (i < 512) {
                int layer = i >> 7, n = i & 127;
                const float* b = (layer == 0) ? b0 : (layer == 1) ? b1 : (layer == 2) ? b2 : b3;
                v = b[n] * SCALE;
            } else {
                int n = i - 512;
                v = (n < 4) ? bm[n] * SCALE : 0.0f;
            }
            wsB[i] = v;
        }
        return;
    }
    // dense brick build
    unsigned e = (unsigned)(bid - 8222) * 256 + threadIdx.x;
    if (e >= DSLOT_TOTAL * 8u) return;
    unsigned brick = e >> 3, j = e & 7u;
    int l = 0;
    #pragma unroll
    for (int i = 1; i < 8; i++) l += (brick >= DOFF16_TAB[i]) ? 1 : 0;
    unsigned local = brick - DOFF16_TAB[l];
    unsigned s = SC_TAB[l], sx4 = SX4_TAB[l];
    unsigned plane = sx4 * s;
    unsigned z = local / plane;
    unsigned rem = local - z * plane;
    unsigned yb = rem / sx4;
    unsigned xs = rem - yb * sx4;
    unsigned x = xs * 4u + (j >> 1);
    unsigned y = yb + (j & 1u);
    unsigned h = (x ^ (y * 2654435761u) ^ (z * 805459861u)) & TMASK;
    const float* src = tables + ((size_t)l * 524288u + h) * 2;
    half2 o; o[0] = (_Float16)(src[0] * SCALE); o[1] = (_Float16)(src[1] * SCALE);
    union { half2 h2; unsigned u; } cv; cv.h2 = o;
    dense[e] = cv.u;
}

// ---------------------------------------------------------------------------
// Legacy prep (weights-only path for fallback tier).
// ---------------------------------------------------------------------------
__global__ void prep_kernel(const float* __restrict__ W0, const float* __restrict__ W1,
                            const float* __restrict__ W2, const float* __restrict__ W3,
                            const float* __restrict__ Wm,
                            const float* __restrict__ b0, const float* __restrict__ b1,
                            const float* __restrict__ b2, const float* __restrict__ b3,
                            const float* __restrict__ bm,
                            _Float16* __restrict__ wsW, float* __restrict__ wsB,
                            const float* __restrict__ tabSrc, _Float16* __restrict__ tabF,
                            int tabBlocks)
{
    if ((int)blockIdx.x < tabBlocks) {
        size_t i = (size_t)blockIdx.x * 256 + threadIdx.x;
        f32x4 v = ((const f32x4*)tabSrc)[i];
        half4 o;
        o[0] = (_Float16)(v.x * SCALE);
        o[1] = (_Float16)(v.y * SCALE);
        o[2] = (_Float16)(v.z * SCALE);
        o[3] = (_Float16)(v.w * SCALE);
        ((half4*)tabF)[i] = o;
        return;
    }
    int gid = ((int)blockIdx.x - tabBlocks) * 256 + threadIdx.x;
    if (gid < 6912) {
        int tile = gid >> 6, lane = gid & 63;
        const float* W; int K, N, toff;
        if (tile < 8)        { W = W0; K = 32;  N = 128; toff = 0;   }
        else if (tile < 40)  { W = W1; K = 128; N = 128; toff = 8;   }
        else if (tile < 72)  { W = W2; K = 128; N = 128; toff = 40;  }
        else if (tile < 104) { W = W3; K = 128; N = 128; toff = 72;  }
        else                 { W = Wm; K = 128; N = 4;   toff = 104; }
        int tt = tile - toff;
        int KT = K >> 5;
        int nt = tt / KT, kt = tt - nt * KT;
        int n = nt * 16 + (lane & 15);
        int kbase = kt * 32 + (lane >> 4) * 8;
        half8 v;
        #pragma unroll
        for (int j = 0; j < 8; j++) {
            int k = kbase + j;
            float w = (n < N) ? W[k * N + n] : 0.0f;
            v[j] = (_Float16)w;
        }
        *(half8*)(wsW + (size_t)gid * 8) = v;
    } else if (gid < 6912 + 528) {
        int i = gid - 6912;
        float v;
        if (i < 512) {
            int layer = i >> 7, n = i & 127;
            const float* b = (layer == 0) ? b0 : (layer == 1) ? b1 : (layer == 2) ? b2 : b3;
            v = b[n] * SCALE;
        } else {
            int n = i - 512;
            v = (n < 4) ? bm[n] * SCALE : 0.0f;
        }
        wsB[i] = v;
    }
}

// ---------------------------------------------------------------------------
// Encode (brick, separate stores) — R7 best-known-good, at structural floor
// per the divergent-line model (validated R2/R4/R5/R6). Load budget per
// pt-level: fine 4x16B + 0.25 avg carry, coarse 2x16B, pos ~coalesced.
// ---------------------------------------------------------------------------
struct PtStateB {
    unsigned fI0[4];
    unsigned xm1, fSel;         // fSel: s0[g] in bits 2g..2g+1, m in 8..9, carry in 10
    unsigned cOff0, cOff1;      // dword offsets of coarse 16B groups (z0, z1)
    float fF[3], fC[3];
};
struct PtLoadsB {
    u32x4 fB[4]; u32x4 cZ[2]; unsigned fX[4];
};

__global__ __launch_bounds__(256) void encode_brick(
    const float* __restrict__ pos, const float* __restrict__ bmn, const float* __restrict__ bmx,
    const _Float16* __restrict__ tabFine, const unsigned* __restrict__ dense,
    _Float16* __restrict__ feat, int npts)
{
    const int lvl0 = (int)(blockIdx.x & 7);
    const int t = (int)threadIdx.x;
    const long pb = (long)(blockIdx.x >> 3) * 2048 + t;   // points pb + k*256, k=0..7
    const float bx = bmn[0], by = bmn[1], bz = bmn[2];
    const float dxr = bmx[0] - bx, dyr = bmx[1] - by, dzr = bmx[2] - bz;
    constexpr float RESL[16] = {16.f, 20.f, 25.f, 32.f, 40.f, 50.f, 64.f, 80.f,
                                101.f, 128.f, 161.f, 203.f, 256.f, 322.f, 406.f, 512.f};
    const int l1 = lvl0 + 8;
    const _Float16* tblB = tabFine + ((size_t)lvl0 << 20);
    const float resF = RESL[l1], resC = RESL[lvl0];
    const unsigned sx4 = SX4_TAB[lvl0];
    const unsigned plane8 = sx4 * SC_TAB[lvl0] * 8u;      // dwords per z-plane of bricks
    const unsigned* dlvl = dense + (size_t)DOFF16_TAB[lvl0] * 8u;

    auto computePt = [&](long p, PtStateB& S) {
        const float nx = (pos[p * 3 + 0] - bx) / dxr;
        const float ny = (pos[p * 3 + 1] - by) / dyr;
        const float nz = (pos[p * 3 + 2] - bz) / dzr;
        {   // fine (hashed, 16B-block trick)
            float xs = nx * resF, ys = ny * resF, zs = nz * resF;
            float fx = floorf(xs), fy = floorf(ys), fz = floorf(zs);
            unsigned xi = (unsigned)fx, yi = (unsigned)fy, zi = (unsigned)fz;
            S.fF[0] = xs - fx; S.fF[1] = ys - fy; S.fF[2] = zs - fz;
            unsigned hy0 = yi * 2654435761u, hy1 = (yi + 1u) * 2654435761u;
            unsigned hz0 = zi * 805459861u,  hz1 = (zi + 1u) * 805459861u;
            unsigned hyz[4] = {hy0 ^ hz0, hy1 ^ hz0, hy0 ^ hz1, hy1 ^ hz1};
            unsigned xm1 = xi ^ (xi + 1u);
            unsigned sel = 0;
            #pragma unroll
            for (int g = 0; g < 4; g++) {
                unsigned i0 = (xi ^ hyz[g]) & TMASK;
                S.fI0[g] = i0;
                sel |= (i0 & 3u) << (2 * g);
            }
            sel |= (xm1 & 3u) << 8;
            if ((xi & 3u) == 3u) sel |= 1024u;
            S.fSel = sel;
            S.xm1 = xm1;
        }
        {   // coarse (y-dup bricks)
            float xs = nx * resC, ys = ny * resC, zs = nz * resC;
            float fx = floorf(xs), fy = floorf(ys), fz = floorf(zs);
            unsigned xi = (unsigned)fx, yi = (unsigned)fy, zi = (unsigned)fz;
            S.fC[0] = xs - fx; S.fC[1] = ys - fy; S.fC[2] = zs - fz;
            unsigned o0 = ((xi >> 2) + sx4 * yi) * 8u + plane8 * zi + (xi & 3u) * 2u;
            S.cOff0 = o0;
            S.cOff1 = o0 + plane8;
        }
    };

    auto issuePt = [&](const PtStateB& S, PtLoadsB& L) {
        #pragma unroll
        for (int g = 0; g < 4; g++)
            L.fB[g] = *(const u32x4*)(tblB + (size_t)(S.fI0[g] >> 2) * 8);
        __builtin_memcpy(&L.cZ[0], dlvl + S.cOff0, 16);
        __builtin_memcpy(&L.cZ[1], dlvl + S.cOff1, 16);
        if (S.fSel & 1024u) {
            #pragma unroll
            for (int g = 0; g < 4; g++)
                L.fX[g] = *(const unsigned*)(tblB + (size_t)((S.fI0[g] ^ S.xm1) & TMASK) * 2);
        }
    };

    auto consumePt = [&](const PtStateB& S, const PtLoadsB& L, long p) {
        {   // fine
            float tx = S.fF[0], ty = S.fF[1], tz = S.fF[2];
            float wyz[4] = {(1.0f - ty) * (1.0f - tz), ty * (1.0f - tz),
                            (1.0f - ty) * tz,          ty * tz};
            unsigned selw = S.fSel;
            unsigned m = (selw >> 8) & 3u;
            bool carry = (selw & 1024u) != 0u;
            float b0 = 0.0f, b1 = 0.0f;
            #pragma unroll
            for (int g = 0; g < 4; g++) {
                u32x4 v = L.fB[g];
                unsigned s0 = (selw >> (2 * g)) & 3u;
                unsigned s1 = s0 ^ m;
                unsigned a0_ = (s0 & 2u) ? v[2] : v[0];
                unsigned b0_ = (s0 & 2u) ? v[3] : v[1];
                unsigned e0  = (s0 & 1u) ? b0_ : a0_;
                unsigned a1_ = (s1 & 2u) ? v[2] : v[0];
                unsigned b1_ = (s1 & 2u) ? v[3] : v[1];
                unsigned e1s = (s1 & 1u) ? b1_ : a1_;
                unsigned e1  = carry ? L.fX[g] : e1s;
                union { unsigned u; half2 h; } u0, u1;
                u0.u = e0; u1.u = e1;
                float w0 = wyz[g] * (1.0f - tx), w1 = wyz[g] * tx;
                b0 += w0 * (float)u0.h[0] + w1 * (float)u1.h[0];
                b1 += w0 * (float)u0.h[1] + w1 * (float)u1.h[1];
            }
            half2 ov2; ov2[0] = (_Float16)b0; ov2[1] = (_Float16)b1;
            union { half2 h; unsigned u; } cv; cv.h = ov2;
            __builtin_nontemporal_store(cv.u, (unsigned*)(feat + ((size_t)l1 * npts + p) * 2));
        }
        {   // coarse: corner g=(ybit, zbit); u0 = cZ[z][ybit], u1 = cZ[z][2+ybit]
            float tx = S.fC[0], ty = S.fC[1], tz = S.fC[2];
            float wyz[4] = {(1.0f - ty) * (1.0f - tz), ty * (1.0f - tz),
                            (1.0f - ty) * tz,          ty * tz};
            float a0 = 0.0f, a1 = 0.0f;
            #pragma unroll
            for (int g = 0; g < 4; g++) {
                union { unsigned u; half2 h; } u0, u1;
                u0.u = L.cZ[g >> 1][g & 1];
                u1.u = L.cZ[g >> 1][2 + (g & 1)];
                float w0 = wyz[g] * (1.0f - tx), w1 = wyz[g] * tx;
                a0 += w0 * (float)u0.h[0] + w1 * (float)u1.h[0];
                a1 += w0 * (float)u0.h[1] + w1 * (float)u1.h[1];
            }
            half2 ov2; ov2[0] = (_Float16)a0; ov2[1] = (_Float16)a1;
            union { half2 h; unsigned u; } cv; cv.h = ov2;
            __builtin_nontemporal_store(cv.u, (unsigned*)(feat + ((size_t)lvl0 * npts + p) * 2));
        }
    };

    // ---- software pipeline: window = 2 points (1 consuming + 1 in flight) ----
    PtStateB sA, sB; PtLoadsB lA, lB;
    computePt(pb + 0 * 256, sA); issuePt(sA, lA);
    computePt(pb + 1 * 256, sB); issuePt(sB, lB);
    #pragma unroll
    for (int k = 0; k < 6; k++) {
        if ((k & 1) == 0) {
            consumePt(sA, lA, pb + (long)k * 256);
            computePt(pb + (long)(k + 2) * 256, sA); issuePt(sA, lA);
        } else {
            consumePt(sB, lB, pb + (long)k * 256);
            computePt(pb + (long)(k + 2) * 256, sB); issuePt(sB, lB);
        }
    }
    consumePt(sA, lA, pb + 6 * 256);
    consumePt(sB, lB, pb + 7 * 256);
}

// ---------------------------------------------------------------------------
// MLP kernel (R7): role-swapped MFMA, 64 points/wave, per-mt publish, b128
// exchange, wave-private, NO barriers. __launch_bounds__(256, 2) pins
// 128 VGPR / 2 waves/SIMD (best measured config).
// ---------------------------------------------------------------------------
#define ELANE 68   // dwords per lane: 64 payload + 4 pad; 272B (16B-aligned)

template<int KT, int TOFF>
__device__ __forceinline__ void layer_fwd4(half8 b[4][4], const half8* __restrict__ wf,
                                           const float* __restrict__ wsB, int li,
                                           unsigned* __restrict__ eb, int lane, int quad,
                                           unsigned srcA, unsigned srcB, int mtbase)
{
    unsigned* wptr = eb + lane * ELANE;
    #pragma unroll
    for (int mt = 0; mt < 8; mt++) {
        f32x4 bias = *(const f32x4*)&wsB[li * 128 + mt * 16 + quad * 4];
        half8 w[KT];
        #pragma unroll
        for (int kt = 0; kt < KT; kt++)
            w[kt] = wf[(size_t)(TOFF + mt * KT + kt) * 64 + lane];
        f32x4 acc[4] = {bias, bias, bias, bias};
        #pragma unroll
        for (int nt = 0; nt < 4; nt++)
            #pragma unroll
            for (int kt = 0; kt < KT; kt++)
                acc[nt] = __builtin_amdgcn_mfma_f32_16x16x32_f16(w[kt], b[nt][kt], acc[nt], 0, 0, 0);
        #pragma unroll
        for (int np = 0; np < 2; np++) {
            union { _Float16 h[8]; u32x4 v; } pk;
            #pragma unroll
            for (int r = 0; r < 4; r++) {
                pk.h[r]     = (_Float16)fmaxf(acc[2 * np][r],     0.0f);
                pk.h[4 + r] = (_Float16)fmaxf(acc[2 * np + 1][r], 0.0f);
            }
            *(u32x4*)(wptr + mt * 8 + np * 4) = pk.v;
        }
    }
    #pragma unroll
    for (int ktp = 0; ktp < 4; ktp++) {
        int mt = 2 * ktp + mtbase;
        u32x4 rA0 = *(const u32x4*)(eb + srcA * ELANE + mt * 8);
        u32x4 rA1 = *(const u32x4*)(eb + srcA * ELANE + mt * 8 + 4);
        u32x4 rB0 = *(const u32x4*)(eb + srcB * ELANE + mt * 8);
        u32x4 rB1 = *(const u32x4*)(eb + srcB * ELANE + mt * 8 + 4);
        union { u32x4 v; half8 h; } c0, c1, c2, c3;
        c0.v = (u32x4){rA0[0], rA0[1], rB0[0], rB0[1]};
        c1.v = (u32x4){rA0[2], rA0[3], rB0[2], rB0[3]};
        c2.v = (u32x4){rA1[0], rA1[1], rB1[0], rB1[1]};
        c3.v = (u32x4){rA1[2], rA1[3], rB1[2], rB1[3]};
        b[0][ktp] = c0.h;
        b[1][ktp] = c1.h;
        b[2][ktp] = c2.h;
        b[3][ktp] = c3.h;
    }
}

__global__ __launch_bounds__(256, 2) void mlp_kernel(
    const unsigned* __restrict__ feat32, const half8* __restrict__ wf,
    const float* __restrict__ wsB, float* __restrict__ out, int npts)
{
    __shared__ __align__(16) unsigned ebuf[4 * 64 * ELANE];
    const int t = threadIdx.x;
    const int lane = t & 63, wv = t >> 6;
    const int col = lane & 15, quad = lane >> 4;
    const long base = (long)blockIdx.x * 256 + wv * 64;
    unsigned* eb = ebuf + wv * (64 * ELANE);
    const int q1 = 2 * (quad & 1);
    const unsigned srcA = (unsigned)(col + 16 * q1);
    const unsigned srcB = (unsigned)(col + 16 * (q1 + 1));
    const int mtbase = quad >> 1;

    half8 b[4][4];
    #pragma unroll
    for (int nt = 0; nt < 4; nt++) {
        const long pt = base + nt * 16 + col;
        union { unsigned u4[4]; half8 v; } cv;
        #pragma unroll
        for (int jj = 0; jj < 4; jj++)
            cv.u4[jj] = feat32[(size_t)(quad * 4 + jj) * npts + pt];
        b[nt][0] = cv.v;
    }

    layer_fwd4<1, 0 >(b, wf, wsB, 0, eb, lane, quad, srcA, srcB, mtbase);  // 32->128
    layer_fwd4<4, 8 >(b, wf, wsB, 1, eb, lane, quad, srcA, srcB, mtbase);  // 128->128
    layer_fwd4<4, 40>(b, wf, wsB, 2, eb, lane, quad, srcA, srcB, mtbase);  // 128->128
    layer_fwd4<4, 72>(b, wf, wsB, 3, eb, lane, quad, srcA, srcB, mtbase);  // 128->128

    f32x4 biaso = *(const f32x4*)&wsB[512 + quad * 4];
    f32x4 acco[4] = {biaso, biaso, biaso, biaso};
    #pragma unroll
    for (int kt = 0; kt < 4; kt++) {
        half8 w = wf[(size_t)(104 + kt) * 64 + lane];
        #pragma unroll
        for (int nt = 0; nt < 4; nt++)
            acco[nt] = __builtin_amdgcn_mfma_f32_16x16x32_f16(w, b[nt][kt], acco[nt], 0, 0, 0);
    }
    if (quad == 0) {
        #pragma unroll
        for (int nt = 0; nt < 4; nt++) {
            f32x4 v;
            #pragma unroll
            for (int r = 0; r < 4; r++) v[r] = acco[nt][r] * INV_SCALE;
            *(f32x4*)(out + (base + nt * 16 + col) * 4) = v;
        }
    }
}

// ---------------------------------------------------------------------------
// Fallback path (ws too small): R1-style fused kernel, unchanged.
// ---------------------------------------------------------------------------
template<int KT, int TOFF, bool RELU>
__device__ __forceinline__ void mlp_layer(_Float16* h, const half8* __restrict__ wf,
                                          const float* __restrict__ wsB, int layerIdx,
                                          int m0, int lane)
{
    const int col = lane & 15, quad = lane >> 4;
    const int sw = (col & 3) << 3;
    half8 a[2][KT];
    #pragma unroll
    for (int mt = 0; mt < 2; mt++)
        #pragma unroll
        for (int kt = 0; kt < KT; kt++)
            a[mt][kt] = *(const half8*)&h[(m0 + mt * 16 + col) * HSTRIDE + ((kt * 32 + quad * 8) ^ sw)];
    f32x4 acc[2][8];
    #pragma unroll
    for (int nt = 0; nt < 8; nt++) {
        float bv = wsB[layerIdx * 128 + nt * 16 + col];
        acc[0][nt] = (f32x4){bv, bv, bv, bv};
        acc[1][nt] = (f32x4){bv, bv, bv, bv};
    }
    #pragma unroll
    for (int nt = 0; nt < 8; nt++) {
        half8 b[KT];
        #pragma unroll
        for (int kt = 0; kt < KT; kt++)
            b[kt] = wf[(size_t)(TOFF + nt * KT + kt) * 64 + lane];
        #pragma unroll
        for (int mt = 0; mt < 2; mt++)
            #pragma unroll
            for (int kt = 0; kt < KT; kt++)
                acc[mt][nt] = __builtin_amdgcn_mfma_f32_16x16x32_f16(a[mt][kt], b[kt], acc[mt][nt], 0, 0, 0);
    }
    #pragma unroll
    for (int mt = 0; mt < 2; mt++)
        #pragma unroll
        for (int nt = 0; nt < 8; nt++) {
            f32x4 v = acc[mt][nt];
            #pragma unroll
            for (int r = 0; r < 4; r++) {
                float x = v[r];
                if (RELU) x = fmaxf(x, 0.0f);
                h[(m0 + mt * 16 + quad * 4 + r) * HSTRIDE + ((nt * 16 + col) ^ (r << 3))] = (_Float16)x;
            }
        }
}

__global__ __launch_bounds__(256, 2) void fused_kernel(
    const float* __restrict__ pos, const float* __restrict__ bmn, const float* __restrict__ bmx,
    const float* __restrict__ tables, const half8* __restrict__ wf, const float* __restrict__ wsB,
    float* __restrict__ out)
{
    __shared__ _Float16 hbuf[128 * HSTRIDE];
    __shared__ float outstage[512];
    const int t = threadIdx.x;
    const long base = (long)blockIdx.x * 128;
    {
        const int p = t >> 1, hh = t & 1;
        const long gp = base + p;
        const float b0x = bmn[0], b0y = bmn[1], b0z = bmn[2];
        const float nx = (pos[gp * 3 + 0] - b0x) / (bmx[0] - b0x);
        const float ny = (pos[gp * 3 + 1] - b0y) / (bmx[1] - b0y);
        const float nz = (pos[gp * 3 + 2] - b0z) / (bmx[2] - b0z);
        constexpr float RLO[8] = {16.f, 20.f, 25.f, 32.f, 40.f, 50.f, 64.f, 80.f};
        constexpr float RHI[8] = {101.f, 128.f, 161.f, 203.f, 256.f, 322.f, 406.f, 512.f};
        half8 fa, fb;
        #pragma unroll
        for (int li = 0; li < 8; li++) {
            const float res = hh ? RHI[li] : RLO[li];
            const float* tbl = tables + ((size_t)(hh * 8 + li) << 20);
            float xs = nx * res, ys = ny * res, zs = nz * res;
            float fx = floorf(xs), fy = floorf(ys), fz = floorf(zs);
            unsigned xi = (unsigned)fx, yi = (unsigned)fy, zi = (unsigned)fz;
            float tx = xs - fx, ty = ys - fy, tz = zs - fz;
            unsigned hx[2] = {xi, xi + 1u};
            unsigned hy[2] = {yi * 2654435761u, (yi + 1u) * 2654435761u};
            unsigned hz[2] = {zi * 805459861u, (zi + 1u) * 805459861u};
            float wx[2] = {1.0f - tx, tx}, wy[2] = {1.0f - ty, ty}, wz[2] = {1.0f - tz, tz};
            float a0 = 0.0f, a1 = 0.0f;
            #pragma unroll
            for (int c = 0; c < 8; c++) {
                unsigned hsh = hx[c & 1] ^ hy[(c >> 1) & 1] ^ hz[c >> 2];
                unsigned idx = hsh & TMASK;
                f32x2 f = *(const f32x2*)(tbl + (size_t)idx * 2);
                float w = wx[c & 1] * wy[(c >> 1) & 1] * wz[c >> 2];
                a0 += w * f.x;
                a1 += w * f.y;
            }
            if (li < 4) { fa[2 * li]       = (_Float16)(a0 * SCALE); fa[2 * li + 1]       = (_Float16)(a1 * SCALE); }
            else        { fb[2 * (li - 4)] = (_Float16)(a0 * SCALE); fb[2 * (li - 4) + 1] = (_Float16)(a1 * SCALE); }
        }
        const int sw = (p & 3) << 3;
        *(half8*)&hbuf[p * HSTRIDE + ((hh * 16) ^ sw)]       = fa;
        *(half8*)&hbuf[p * HSTRIDE + (((hh * 16) + 8) ^ sw)] = fb;
    }
    __syncthreads();
    {
        const int lane = t & 63;
        const int m0 = (t >> 6) * 32;
        mlp_layer<1, 0,   true>(hbuf, wf, wsB, 0, m0, lane);
        mlp_layer<4, 8,   true>(hbuf, wf, wsB, 1, m0, lane);
        mlp_layer<4, 40,  true>(hbuf, wf, wsB, 2, m0, lane);
        mlp_layer<4, 72,  true>(hbuf, wf, wsB, 3, m0, lane);
        const int col = lane & 15, quad = lane >> 4;
        const int sw = (col & 3) << 3;
        half8 a[2][4];
        #pragma unroll
        for (int mt = 0; mt < 2; mt++)
            #pragma unroll
            for (int kt = 0; kt < 4; kt++)
                a[mt][kt] = *(const half8*)&hbuf[(m0 + mt * 16 + col) * HSTRIDE + ((kt * 32 + quad * 8) ^ sw)];
        float bv = wsB[512 + col];
        f32x4 acc[2] = {(f32x4){bv, bv, bv, bv}, (f32x4){bv, bv, bv, bv}};
        #pragma unroll
        for (int kt = 0; kt < 4; kt++) {
            half8 bfr = wf[(size_t)(104 + kt) * 64 + lane];
            #pragma unroll
            for (int mt = 0; mt < 2; mt++)
                acc[mt] = __builtin_amdgcn_mfma_f32_16x16x32_f16(a[mt][kt], bfr, acc[mt], 0, 0, 0);
        }
        if (col < 4) {
            #pragma unroll
            for (int mt = 0; mt < 2; mt++)
                #pragma unroll
                for (int r = 0; r < 4; r++)
                    outstage[(m0 + mt * 16 + quad * 4 + r) * 4 + col] = acc[mt][r] * INV_SCALE;
        }
    }
    __syncthreads();
    if (t < 128) {
        f32x4 v = ((const f32x4*)outstage)[t];
        *(f32x4*)(out + (base + t) * 4) = v;
    }
}

extern "C" void kernel_launch(void* const* d_in, const int* in_sizes, int n_in,
                              void* d_out, int out_size, void* d_ws, size_t ws_size,
                              hipStream_t stream) {
    const float* pos    = (const float*)d_in[0];
    const float* bmn    = (const float*)d_in[1];
    const float* bmx    = (const float*)d_in[2];
    const float* tables = (const float*)d_in[3];
    const float* W0 = (const float*)d_in[4];
    const float* b0 = (const float*)d_in[5];
    const float* W1 = (const float*)d_in[6];
    const float* b1 = (const float*)d_in[7];
    const float* W2 = (const float*)d_in[8];
    const float* b2 = (const float*)d_in[9];
    const float* W3 = (const float*)d_in[10];
    const float* b3 = (const float*)d_in[11];
    const float* Wm = (const float*)d_in[12];
    const float* bm = (const float*)d_in[13];

    const int N = in_sizes[0] / 3;
    const size_t featBytes    = (size_t)N * 16 * 4;             // [16][N] f16x2
    const size_t tabFineBytes = (size_t)8 * 524288 * 2 * 2;     // 16 MB f16, levels 8-15
    const size_t denseBytesB  = ((size_t)DSLOT_TOTAL * 32 + 255) & ~(size_t)255;  // ~9.3 MB bricks
    const size_t needB = featBytes + tabFineBytes + denseBytesB + 110592 + 2112;

    if (ws_size >= needB && (N % 2048) == 0) {
        _Float16* feat  = (_Float16*)d_ws;
        _Float16* tabF  = (_Float16*)((char*)d_ws + featBytes);
        unsigned* dense = (unsigned*)((char*)d_ws + featBytes + tabFineBytes);
        _Float16* wsW   = (_Float16*)((char*)d_ws + featBytes + tabFineBytes + denseBytesB);
        float*    wsB   = (float*)((char*)d_ws + featBytes + tabFineBytes + denseBytesB + 110592);
        prep_dense_kernel<<<8192 + 30 + (DSLOT_TOTAL * 8 + 255) / 256, 256, 0, stream>>>(
            W0, W1, W2, W3, Wm, b0, b1, b2, b3, bm, wsW, wsB, tables, tabF, dense);
        encode_brick<<<(N / 2048) * 8, 256, 0, stream>>>(pos, bmn, bmx, tabF,
                                                         dense, feat, N);
        mlp_kernel<<<N / 256, 256, 0, stream>>>((const unsigned*)feat, (const half8*)wsW,
                                                wsB, (float*)d_out, N);
    } else {
        _Float16* wsW = (_Float16*)d_ws;
        float*    wsB = (float*)((char*)d_ws + 110592);
        prep_kernel<<<30, 256, 0, stream>>>(W0, W1, W2, W3, Wm, b0, b1, b2, b3, bm,
                                            wsW, wsB, tables, (_Float16*)nullptr, 0);
        fused_kernel<<<N / 128, 256, 0, stream>>>(pos, bmn, bmx, tables,
                                                  (const half8*)wsW, wsB, (float*)d_out);
    }
}